// Round 1
// baseline (968.739 us; speedup 1.0000x reference)
//
#include <hip/hip_runtime.h>

#define NN 50000
#define NE 800000
#define DD 64
#define NB 196   // ceil(NN/256)

// ---- CSR build: histogram of dst ----
__global__ __launch_bounds__(256) void k_hist(const int* __restrict__ dst,
                                              int* __restrict__ cnt) {
    int e = blockIdx.x * 256 + threadIdx.x;
    if (e < NE) atomicAdd(&cnt[dst[e]], 1);
}

// ---- scan pass 1: per-block sums of cnt ----
__global__ __launch_bounds__(256) void k_block_sum(const int* __restrict__ cnt,
                                                   int* __restrict__ bsum) {
    __shared__ int s[256];
    int i = blockIdx.x * 256 + threadIdx.x;
    s[threadIdx.x] = (i < NN) ? cnt[i] : 0;
    __syncthreads();
    for (int o = 128; o > 0; o >>= 1) {
        if (threadIdx.x < o) s[threadIdx.x] += s[threadIdx.x + o];
        __syncthreads();
    }
    if (threadIdx.x == 0) bsum[blockIdx.x] = s[0];
}

// ---- scan pass 2: exclusive scan of NB block sums (single block) ----
__global__ __launch_bounds__(256) void k_scan_bsum(int* __restrict__ bsum) {
    __shared__ int s[256];
    int t = threadIdx.x;
    int v = (t < NB) ? bsum[t] : 0;
    s[t] = v;
    __syncthreads();
    for (int o = 1; o < 256; o <<= 1) {
        int x = (t >= o) ? s[t - o] : 0;
        __syncthreads();
        s[t] += x;
        __syncthreads();
    }
    if (t < NB) bsum[t] = s[t] - v;  // exclusive
}

// ---- scan pass 3: final exclusive offsets; write row_start and cursor ----
__global__ __launch_bounds__(256) void k_scan_final(const int* __restrict__ cnt,
                                                    const int* __restrict__ bsum,
                                                    int* __restrict__ row_start,
                                                    int* __restrict__ cursor) {
    __shared__ int s[256];
    int t = threadIdx.x;
    int i = blockIdx.x * 256 + t;
    int v = (i < NN) ? cnt[i] : 0;
    s[t] = v;
    __syncthreads();
    for (int o = 1; o < 256; o <<= 1) {
        int x = (t >= o) ? s[t - o] : 0;
        __syncthreads();
        s[t] += x;
        __syncthreads();
    }
    int excl = s[t] - v + bsum[blockIdx.x];
    if (i < NN) {
        row_start[i] = excl;
        cursor[i]    = excl;
        if (i == NN - 1) row_start[NN] = excl + v;  // == NE
    }
}

// ---- counting sort: scatter edge ids into dst-sorted order ----
__global__ __launch_bounds__(256) void k_reorder(const int* __restrict__ dst,
                                                 int* __restrict__ cursor,
                                                 int* __restrict__ eid) {
    int e = blockIdx.x * 256 + threadIdx.x;
    if (e < NE) {
        int pos = atomicAdd(&cursor[dst[e]], 1);
        eid[pos] = e;
    }
}

// ---- gather-sum: one wave per node, lane l accumulates feature l ----
__global__ __launch_bounds__(256) void k_gather(const float* __restrict__ ef,
                                                const int* __restrict__ row_start,
                                                const int* __restrict__ eid,
                                                float* __restrict__ nx) {
    int lane = threadIdx.x & 63;
    int n = blockIdx.x * 4 + (threadIdx.x >> 6);
    if (n >= NN) return;
    int beg = row_start[n], end = row_start[n + 1];
    float a0 = 0.f, a1 = 0.f, a2 = 0.f, a3 = 0.f;
    int i = beg;
    for (; i + 3 < end; i += 4) {
        int e0 = eid[i], e1 = eid[i + 1], e2 = eid[i + 2], e3 = eid[i + 3];
        a0 += ef[(long)e0 * DD + lane];
        a1 += ef[(long)e1 * DD + lane];
        a2 += ef[(long)e2 * DD + lane];
        a3 += ef[(long)e3 * DD + lane];
    }
    for (; i < end; ++i) {
        a0 += ef[(long)eid[i] * DD + lane];
    }
    nx[(long)n * DD + lane] = (a0 + a1) + (a2 + a3);
}

// ---- h_pre = node_x @ W1 ----
// Two passes of 32 output features each: acc[32] fits comfortably in VGPRs
// (the old acc[64] version ran with VGPR_Count=64 -> accumulator in scratch,
// 2.5x HBM write amplification). kc loop intentionally rolled: small body,
// guaranteed-unrolled j loop, all acc indices compile-time constant.
__global__ __launch_bounds__(256, 4) void k_node_mlp(const float* __restrict__ nx,
                                                     const float* __restrict__ W1,
                                                     float* __restrict__ hp) {
    int n = blockIdx.x * 256 + threadIdx.x;
    if (n >= NN) return;
    const float4* xr = (const float4*)(nx + (long)n * DD);
    float4* o = (float4*)(hp + (long)n * DD);
#pragma unroll
    for (int jb = 0; jb < 2; ++jb) {
        float acc[32];
#pragma unroll
        for (int j = 0; j < 32; ++j) acc[j] = 0.f;
        for (int kc = 0; kc < DD / 4; ++kc) {
            float4 x = xr[kc];
            const float* w0 = W1 + (4 * kc + 0) * DD + jb * 32;  // wave-uniform -> s_load
            const float* w1 = W1 + (4 * kc + 1) * DD + jb * 32;
            const float* w2 = W1 + (4 * kc + 2) * DD + jb * 32;
            const float* w3 = W1 + (4 * kc + 3) * DD + jb * 32;
#pragma unroll
            for (int j = 0; j < 32; ++j) {
                float a = acc[j];
                a = fmaf(x.x, w0[j], a);
                a = fmaf(x.y, w1[j], a);
                a = fmaf(x.z, w2[j], a);
                a = fmaf(x.w, w3[j], a);
                acc[j] = a;
            }
        }
#pragma unroll
        for (int j = 0; j < 32; j += 4) {
            float4 r;
            r.x = acc[j + 0]; r.y = acc[j + 1]; r.z = acc[j + 2]; r.w = acc[j + 3];
            o[(jb * 32 + j) >> 2] = r;
        }
    }
}

// ---- edge_out = 0.5*(relu(h_pre[src]+h_pre[dst]+b1) @ W2 + b2) ----
// Same two-pass/acc[32] structure. h is recomputed per pass (second-pass
// ps/pd reads hit L1/L2); total FMA count is unchanged, scratch traffic -> 0.
__global__ __launch_bounds__(256, 4) void k_edge_mlp(const float* __restrict__ hp,
                                                     const int* __restrict__ src,
                                                     const int* __restrict__ dst,
                                                     const float* __restrict__ b1,
                                                     const float* __restrict__ W2,
                                                     const float* __restrict__ b2,
                                                     float* __restrict__ out) {
    int e = blockIdx.x * 256 + threadIdx.x;
    if (e >= NE) return;
    int s = src[e], d = dst[e];
    const float4* ps = (const float4*)(hp + (long)s * DD);
    const float4* pd = (const float4*)(hp + (long)d * DD);
    float4* o = (float4*)(out + (long)e * DD);
#pragma unroll
    for (int jb = 0; jb < 2; ++jb) {
        float acc[32];
#pragma unroll
        for (int j = 0; j < 32; ++j) acc[j] = 0.f;
        for (int kc = 0; kc < DD / 4; ++kc) {
            float4 a = ps[kc];
            float4 b = pd[kc];
            float4 bb = ((const float4*)b1)[kc];   // uniform -> s_load
            float h0 = fmaxf(a.x + b.x + bb.x, 0.f);
            float h1 = fmaxf(a.y + b.y + bb.y, 0.f);
            float h2 = fmaxf(a.z + b.z + bb.z, 0.f);
            float h3 = fmaxf(a.w + b.w + bb.w, 0.f);
            const float* w0 = W2 + (4 * kc + 0) * DD + jb * 32;  // wave-uniform -> s_load
            const float* w1 = W2 + (4 * kc + 1) * DD + jb * 32;
            const float* w2 = W2 + (4 * kc + 2) * DD + jb * 32;
            const float* w3 = W2 + (4 * kc + 3) * DD + jb * 32;
#pragma unroll
            for (int j = 0; j < 32; ++j) {
                float v = acc[j];
                v = fmaf(h0, w0[j], v);
                v = fmaf(h1, w1[j], v);
                v = fmaf(h2, w2[j], v);
                v = fmaf(h3, w3[j], v);
                acc[j] = v;
            }
        }
#pragma unroll
        for (int j = 0; j < 32; j += 4) {
            float4 r;
            r.x = 0.5f * (acc[j + 0] + b2[jb * 32 + j + 0]);
            r.y = 0.5f * (acc[j + 1] + b2[jb * 32 + j + 1]);
            r.z = 0.5f * (acc[j + 2] + b2[jb * 32 + j + 2]);
            r.w = 0.5f * (acc[j + 3] + b2[jb * 32 + j + 3]);
            o[(jb * 32 + j) >> 2] = r;
        }
    }
}

extern "C" void kernel_launch(void* const* d_in, const int* in_sizes, int n_in,
                              void* d_out, int out_size, void* d_ws, size_t ws_size,
                              hipStream_t stream) {
    const float* edge_feat = (const float*)d_in[0];
    const int*   src       = (const int*)d_in[1];
    const int*   dst       = (const int*)d_in[2];
    const float* W1        = (const float*)d_in[3];
    const float* b1        = (const float*)d_in[4];
    const float* W2        = (const float*)d_in[5];
    const float* b2        = (const float*)d_in[6];
    float* out = (float*)d_out;

    char* ws = (char*)d_ws;
    size_t off = 0;
    float* node_x = (float*)(ws + off); off += (size_t)NN * DD * 4;   // 12.8 MB
    float* h_pre  = (float*)(ws + off); off += (size_t)NN * DD * 4;   // 12.8 MB
    int* cnt       = (int*)(ws + off); off += (size_t)NN * 4;
    int* row_start = (int*)(ws + off); off += (size_t)(NN + 1) * 4;
    int* cursor    = (int*)(ws + off); off += (size_t)NN * 4;
    int* bsum      = (int*)(ws + off); off += 256 * 4;
    int* eid       = (int*)(ws + off); off += (size_t)NE * 4;         // 3.2 MB

    hipMemsetAsync(cnt, 0, (size_t)NN * 4, stream);
    k_hist<<<(NE + 255) / 256, 256, 0, stream>>>(dst, cnt);
    k_block_sum<<<NB, 256, 0, stream>>>(cnt, bsum);
    k_scan_bsum<<<1, 256, 0, stream>>>(bsum);
    k_scan_final<<<NB, 256, 0, stream>>>(cnt, bsum, row_start, cursor);
    k_reorder<<<(NE + 255) / 256, 256, 0, stream>>>(dst, cursor, eid);
    k_gather<<<(NN + 3) / 4, 256, 0, stream>>>(edge_feat, row_start, eid, node_x);
    k_node_mlp<<<(NN + 255) / 256, 256, 0, stream>>>(node_x, W1, h_pre);
    k_edge_mlp<<<(NE + 255) / 256, 256, 0, stream>>>(h_pre, src, dst, b1, W2, b2, out);
}

// Round 2
// 725.862 us; speedup vs baseline: 1.3346x; 1.3346x over previous
//
#include <hip/hip_runtime.h>

#define NN 50000
#define NE 800000
#define DD 64
#define NB 196   // ceil(NN/256)

// ---- CSR build: histogram of dst ----
__global__ __launch_bounds__(256) void k_hist(const int* __restrict__ dst,
                                              int* __restrict__ cnt) {
    int e = blockIdx.x * 256 + threadIdx.x;
    if (e < NE) atomicAdd(&cnt[dst[e]], 1);
}

// ---- scan pass 1: per-block sums of cnt ----
__global__ __launch_bounds__(256) void k_block_sum(const int* __restrict__ cnt,
                                                   int* __restrict__ bsum) {
    __shared__ int s[256];
    int i = blockIdx.x * 256 + threadIdx.x;
    s[threadIdx.x] = (i < NN) ? cnt[i] : 0;
    __syncthreads();
    for (int o = 128; o > 0; o >>= 1) {
        if (threadIdx.x < o) s[threadIdx.x] += s[threadIdx.x + o];
        __syncthreads();
    }
    if (threadIdx.x == 0) bsum[blockIdx.x] = s[0];
}

// ---- scan pass 2: exclusive scan of NB block sums (single block) ----
__global__ __launch_bounds__(256) void k_scan_bsum(int* __restrict__ bsum) {
    __shared__ int s[256];
    int t = threadIdx.x;
    int v = (t < NB) ? bsum[t] : 0;
    s[t] = v;
    __syncthreads();
    for (int o = 1; o < 256; o <<= 1) {
        int x = (t >= o) ? s[t - o] : 0;
        __syncthreads();
        s[t] += x;
        __syncthreads();
    }
    if (t < NB) bsum[t] = s[t] - v;  // exclusive
}

// ---- scan pass 3: final exclusive offsets; write row_start and cursor ----
__global__ __launch_bounds__(256) void k_scan_final(const int* __restrict__ cnt,
                                                    const int* __restrict__ bsum,
                                                    int* __restrict__ row_start,
                                                    int* __restrict__ cursor) {
    __shared__ int s[256];
    int t = threadIdx.x;
    int i = blockIdx.x * 256 + t;
    int v = (i < NN) ? cnt[i] : 0;
    s[t] = v;
    __syncthreads();
    for (int o = 1; o < 256; o <<= 1) {
        int x = (t >= o) ? s[t - o] : 0;
        __syncthreads();
        s[t] += x;
        __syncthreads();
    }
    int excl = s[t] - v + bsum[blockIdx.x];
    if (i < NN) {
        row_start[i] = excl;
        cursor[i]    = excl;
        if (i == NN - 1) row_start[NN] = excl + v;  // == NE
    }
}

// ---- counting sort: scatter edge ids into dst-sorted order ----
__global__ __launch_bounds__(256) void k_reorder(const int* __restrict__ dst,
                                                 int* __restrict__ cursor,
                                                 int* __restrict__ eid) {
    int e = blockIdx.x * 256 + threadIdx.x;
    if (e < NE) {
        int pos = atomicAdd(&cursor[dst[e]], 1);
        eid[pos] = e;
    }
}

// ---- gather-sum: one wave per node, lane l accumulates feature l ----
__global__ __launch_bounds__(256) void k_gather(const float* __restrict__ ef,
                                                const int* __restrict__ row_start,
                                                const int* __restrict__ eid,
                                                float* __restrict__ nx) {
    int lane = threadIdx.x & 63;
    int n = blockIdx.x * 4 + (threadIdx.x >> 6);
    if (n >= NN) return;
    int beg = row_start[n], end = row_start[n + 1];
    float a0 = 0.f, a1 = 0.f, a2 = 0.f, a3 = 0.f;
    int i = beg;
    for (; i + 3 < end; i += 4) {
        int e0 = eid[i], e1 = eid[i + 1], e2 = eid[i + 2], e3 = eid[i + 3];
        a0 += ef[(long)e0 * DD + lane];
        a1 += ef[(long)e1 * DD + lane];
        a2 += ef[(long)e2 * DD + lane];
        a3 += ef[(long)e3 * DD + lane];
    }
    for (; i < end; ++i) {
        a0 += ef[(long)eid[i] * DD + lane];
    }
    nx[(long)n * DD + lane] = (a0 + a1) + (a2 + a3);
}

// ---- h_pre = node_x @ W1 ----
// W1 staged in LDS (16 KB). Inner reads are wave-uniform-address ds_read_b128
// broadcasts (conflict-free), so there is NO global/scalar load pressure in
// the inner loop -> acc[64] stays in VGPRs. launch_bounds(256,2) gives the
// allocator a 256-VGPR budget. LDS load happens BEFORE the n-guard so the
// barrier is never divergent.
__global__ __launch_bounds__(256, 2) void k_node_mlp(const float* __restrict__ nx,
                                                     const float* __restrict__ W1,
                                                     float* __restrict__ hp) {
    __shared__ float4 sW[DD * DD / 4];  // 16 KB, row-major float4
    for (int t = threadIdx.x; t < DD * DD / 4; t += 256)
        sW[t] = ((const float4*)W1)[t];
    __syncthreads();

    int n = blockIdx.x * 256 + threadIdx.x;
    if (n >= NN) return;
    const float4* xr = (const float4*)(nx + (long)n * DD);
    float acc[DD];
#pragma unroll
    for (int j = 0; j < DD; ++j) acc[j] = 0.f;
    for (int kc = 0; kc < DD / 4; ++kc) {   // rolled: keeps pressure local
        float4 x = xr[kc];
        const float4* w0 = &sW[(4 * kc + 0) * (DD / 4)];
        const float4* w1 = &sW[(4 * kc + 1) * (DD / 4)];
        const float4* w2 = &sW[(4 * kc + 2) * (DD / 4)];
        const float4* w3 = &sW[(4 * kc + 3) * (DD / 4)];
#pragma unroll
        for (int q = 0; q < DD / 4; ++q) {
            float4 a0 = w0[q], a1 = w1[q], a2 = w2[q], a3 = w3[q];
            acc[4 * q + 0] = fmaf(x.x, a0.x, fmaf(x.y, a1.x, fmaf(x.z, a2.x, fmaf(x.w, a3.x, acc[4 * q + 0]))));
            acc[4 * q + 1] = fmaf(x.x, a0.y, fmaf(x.y, a1.y, fmaf(x.z, a2.y, fmaf(x.w, a3.y, acc[4 * q + 1]))));
            acc[4 * q + 2] = fmaf(x.x, a0.z, fmaf(x.y, a1.z, fmaf(x.z, a2.z, fmaf(x.w, a3.z, acc[4 * q + 2]))));
            acc[4 * q + 3] = fmaf(x.x, a0.w, fmaf(x.y, a1.w, fmaf(x.z, a2.w, fmaf(x.w, a3.w, acc[4 * q + 3]))));
        }
    }
    float4* o = (float4*)(hp + (long)n * DD);
#pragma unroll
    for (int j = 0; j < DD; j += 4) {
        float4 r;
        r.x = acc[j + 0]; r.y = acc[j + 1]; r.z = acc[j + 2]; r.w = acc[j + 3];
        o[j >> 2] = r;
    }
}

// ---- edge_out = 0.5*(relu(h_pre[src]+h_pre[dst]+b1) @ W2 + b2) ----
// Same LDS-broadcast structure: W2 in LDS, acc[64] in registers, single pass.
__global__ __launch_bounds__(256, 2) void k_edge_mlp(const float* __restrict__ hp,
                                                     const int* __restrict__ src,
                                                     const int* __restrict__ dst,
                                                     const float* __restrict__ b1,
                                                     const float* __restrict__ W2,
                                                     const float* __restrict__ b2,
                                                     float* __restrict__ out) {
    __shared__ float4 sW[DD * DD / 4];  // 16 KB
    for (int t = threadIdx.x; t < DD * DD / 4; t += 256)
        sW[t] = ((const float4*)W2)[t];
    __syncthreads();

    int e = blockIdx.x * 256 + threadIdx.x;
    if (e >= NE) return;
    int s = src[e], d = dst[e];
    const float4* ps = (const float4*)(hp + (long)s * DD);
    const float4* pd = (const float4*)(hp + (long)d * DD);
    float acc[DD];
#pragma unroll
    for (int j = 0; j < DD; ++j) acc[j] = 0.f;
    for (int kc = 0; kc < DD / 4; ++kc) {   // rolled
        float4 a = ps[kc];
        float4 b = pd[kc];
        float4 bb = ((const float4*)b1)[kc];   // uniform, tiny
        float h0 = fmaxf(a.x + b.x + bb.x, 0.f);
        float h1 = fmaxf(a.y + b.y + bb.y, 0.f);
        float h2 = fmaxf(a.z + b.z + bb.z, 0.f);
        float h3 = fmaxf(a.w + b.w + bb.w, 0.f);
        const float4* w0 = &sW[(4 * kc + 0) * (DD / 4)];
        const float4* w1 = &sW[(4 * kc + 1) * (DD / 4)];
        const float4* w2 = &sW[(4 * kc + 2) * (DD / 4)];
        const float4* w3 = &sW[(4 * kc + 3) * (DD / 4)];
#pragma unroll
        for (int q = 0; q < DD / 4; ++q) {
            float4 x0 = w0[q], x1 = w1[q], x2 = w2[q], x3 = w3[q];
            acc[4 * q + 0] = fmaf(h0, x0.x, fmaf(h1, x1.x, fmaf(h2, x2.x, fmaf(h3, x3.x, acc[4 * q + 0]))));
            acc[4 * q + 1] = fmaf(h0, x0.y, fmaf(h1, x1.y, fmaf(h2, x2.y, fmaf(h3, x3.y, acc[4 * q + 1]))));
            acc[4 * q + 2] = fmaf(h0, x0.z, fmaf(h1, x1.z, fmaf(h2, x2.z, fmaf(h3, x3.z, acc[4 * q + 2]))));
            acc[4 * q + 3] = fmaf(h0, x0.w, fmaf(h1, x1.w, fmaf(h2, x2.w, fmaf(h3, x3.w, acc[4 * q + 3]))));
        }
    }
    float4* o = (float4*)(out + (long)e * DD);
#pragma unroll
    for (int j = 0; j < DD; j += 4) {
        float4 r;
        r.x = 0.5f * (acc[j + 0] + b2[j + 0]);
        r.y = 0.5f * (acc[j + 1] + b2[j + 1]);
        r.z = 0.5f * (acc[j + 2] + b2[j + 2]);
        r.w = 0.5f * (acc[j + 3] + b2[j + 3]);
        o[j >> 2] = r;
    }
}

extern "C" void kernel_launch(void* const* d_in, const int* in_sizes, int n_in,
                              void* d_out, int out_size, void* d_ws, size_t ws_size,
                              hipStream_t stream) {
    const float* edge_feat = (const float*)d_in[0];
    const int*   src       = (const int*)d_in[1];
    const int*   dst       = (const int*)d_in[2];
    const float* W1        = (const float*)d_in[3];
    const float* b1        = (const float*)d_in[4];
    const float* W2        = (const float*)d_in[5];
    const float* b2        = (const float*)d_in[6];
    float* out = (float*)d_out;

    char* ws = (char*)d_ws;
    size_t off = 0;
    float* node_x = (float*)(ws + off); off += (size_t)NN * DD * 4;   // 12.8 MB
    float* h_pre  = (float*)(ws + off); off += (size_t)NN * DD * 4;   // 12.8 MB
    int* cnt       = (int*)(ws + off); off += (size_t)NN * 4;
    int* row_start = (int*)(ws + off); off += (size_t)(NN + 1) * 4;
    int* cursor    = (int*)(ws + off); off += (size_t)NN * 4;
    int* bsum      = (int*)(ws + off); off += 256 * 4;
    int* eid       = (int*)(ws + off); off += (size_t)NE * 4;         // 3.2 MB

    hipMemsetAsync(cnt, 0, (size_t)NN * 4, stream);
    k_hist<<<(NE + 255) / 256, 256, 0, stream>>>(dst, cnt);
    k_block_sum<<<NB, 256, 0, stream>>>(cnt, bsum);
    k_scan_bsum<<<1, 256, 0, stream>>>(bsum);
    k_scan_final<<<NB, 256, 0, stream>>>(cnt, bsum, row_start, cursor);
    k_reorder<<<(NE + 255) / 256, 256, 0, stream>>>(dst, cursor, eid);
    k_gather<<<(NN + 3) / 4, 256, 0, stream>>>(edge_feat, row_start, eid, node_x);
    k_node_mlp<<<(NN + 255) / 256, 256, 0, stream>>>(node_x, W1, h_pre);
    k_edge_mlp<<<(NE + 255) / 256, 256, 0, stream>>>(h_pre, src, dst, b1, W2, b2, out);
}